// Round 1
// baseline (6422.563 us; speedup 1.0000x reference)
//
#include <hip/hip_runtime.h>

// GIN baseline: fp32 everywhere, atomics for scatter/pool/stats.
// ws layout: h | agg | t (each N*64 f32), then stats[4][2][2][64], ss[4][2][128],
//            pooled_x[G*32], pooled_layers[4][G*64]

#define BN_EPS 1e-5f

// ---------------------------------------------------------------------------
// GEMM: out[n][d] = transform(in)[n][:K] @ W[K][64] + bias[d]
// MODE 0: in = A               (encoder)
// MODE 1: in = A + B           (h + agg)
// MODE 2: in = relu(A*scale[k] + shift[k])   (BN+ReLU on the fly)
// STATS: accumulate per-column sum / sumsq of the OUTPUT into stat_sum/stat_sumsq
// Block: 256 threads = 64 features x 4 node-lanes; 32 nodes per block, 8 nodes/thread.
template<int K, int MODE, bool STATS>
__global__ __launch_bounds__(256)
void mlp_gemm(const float* __restrict__ A, const float* __restrict__ B,
              const float* __restrict__ scale_shift,
              const float* __restrict__ W, const float* __restrict__ bias,
              float* __restrict__ out,
              float* __restrict__ stat_sum, float* __restrict__ stat_sumsq)
{
    __shared__ float W_lds[K * 64];
    __shared__ float in_lds[32 * K];
    const int tid = threadIdx.x;
    const int d   = tid & 63;
    const int nl  = tid >> 6;           // 0..3
    const int nb  = blockIdx.x * 32;    // node base (N divisible by 32)

    #pragma unroll
    for (int i = tid; i < K * 64; i += 256) W_lds[i] = W[i];

    const float* Ab = A + (size_t)nb * K;
    #pragma unroll
    for (int i = tid; i < 32 * K; i += 256) {
        float v = Ab[i];
        if (MODE == 1) {
            const float* Bb = B + (size_t)nb * K;
            v += Bb[i];
        }
        if (MODE == 2) {
            int k = i % K;
            v = fmaxf(v * scale_shift[k] + scale_shift[64 + k], 0.f);
        }
        in_lds[i] = v;
    }
    __syncthreads();

    float acc[8];
    const float bv = bias[d];
    #pragma unroll
    for (int nn = 0; nn < 8; nn++) acc[nn] = bv;

    #pragma unroll
    for (int k = 0; k < K; k++) {
        float w = W_lds[k * 64 + d];
        #pragma unroll
        for (int nn = 0; nn < 8; nn++)
            acc[nn] = fmaf(in_lds[(nl + nn * 4) * K + k], w, acc[nn]);
    }

    float* ob = out + (size_t)nb * 64;
    #pragma unroll
    for (int nn = 0; nn < 8; nn++)
        ob[(nl + nn * 4) * 64 + d] = acc[nn];

    if (STATS) {
        float s1 = 0.f, s2 = 0.f;
        #pragma unroll
        for (int nn = 0; nn < 8; nn++) { s1 += acc[nn]; s2 += acc[nn] * acc[nn]; }
        __syncthreads();                    // done reading in_lds; reuse it
        in_lds[tid]       = s1;
        in_lds[256 + tid] = s2;
        __syncthreads();
        if (nl == 0) {
            float t1 = in_lds[d] + in_lds[64 + d] + in_lds[128 + d] + in_lds[192 + d];
            float t2 = in_lds[256 + d] + in_lds[320 + d] + in_lds[384 + d] + in_lds[448 + d];
            unsafeAtomicAdd(&stat_sum[d],   t1);
            unsafeAtomicAdd(&stat_sumsq[d], t2);
        }
    }
}

// ---------------------------------------------------------------------------
// agg[dst[e]][:] += h[src[e]][:]   — 16 threads per edge, float4 gather, f32 atomics
__global__ __launch_bounds__(256)
void scatter_add(const int* __restrict__ src, const int* __restrict__ dst,
                 const float* __restrict__ h, float* __restrict__ agg, int E)
{
    int tid = blockIdx.x * 256 + threadIdx.x;
    int e = tid >> 4;
    if (e >= E) return;
    int c = (tid & 15) * 4;
    int s = src[e], d = dst[e];
    const float4 v = *(const float4*)(h + (size_t)s * 64 + c);
    float* p = agg + (size_t)d * 64 + c;
    unsafeAtomicAdd(p + 0, v.x);
    unsafeAtomicAdd(p + 1, v.y);
    unsafeAtomicAdd(p + 2, v.z);
    unsafeAtomicAdd(p + 3, v.w);
}

// ---------------------------------------------------------------------------
// fold BN stats + gamma/beta into scale/shift: y = t*scale + shift
__global__ void bn_finalize(const float* __restrict__ sum, const float* __restrict__ sumsq,
                            const float* __restrict__ gamma, const float* __restrict__ beta,
                            float* __restrict__ ss, float invN)
{
    int d = threadIdx.x;  // 64 threads
    float mu   = sum[d] * invN;
    float var  = sumsq[d] * invN - mu * mu;
    float rstd = rsqrtf(var + BN_EPS);
    float s    = gamma[d] * rstd;
    ss[d]      = s;
    ss[64 + d] = beta[d] - s * mu;
}

// ---------------------------------------------------------------------------
// h = relu(t2*scale+shift); pooled[batch[n]][d] += h   (outer BN+ReLU + JK pooling)
__global__ __launch_bounds__(256)
void bn_relu_pool(const float* __restrict__ t2, const float* __restrict__ ss,
                  const int* __restrict__ batch, float* __restrict__ h,
                  float* __restrict__ pooled, int N)
{
    int tid = blockIdx.x * 256 + threadIdx.x;
    int n = tid >> 6;
    if (n >= N) return;
    int d = tid & 63;
    float v = fmaxf(t2[tid] * ss[d] + ss[64 + d], 0.f);
    h[tid] = v;
    unsafeAtomicAdd(&pooled[(size_t)batch[n] * 64 + d], v);
}

// pooled_x[batch[n]][f] += x[n][f]
__global__ __launch_bounds__(256)
void pool_x(const float* __restrict__ x, const int* __restrict__ batch,
            float* __restrict__ px, int N)
{
    int tid = blockIdx.x * 256 + threadIdx.x;
    int n = tid >> 5;
    if (n >= N) return;
    int f = tid & 31;
    unsafeAtomicAdd(&px[(size_t)batch[n] * 32 + f], x[tid]);
}

// ---------------------------------------------------------------------------
// out[g][c] = px[g]@fcW0[:,c] + fcb0[c] + sum_i pl[i][g]@fcW[i][:,c] + fcb[i][c]
// plus out[G*10 + g] = (float)y[g]
__global__ __launch_bounds__(256)
void head_kernel(const float* __restrict__ px, const float* __restrict__ pl,
                 const float* __restrict__ fcW0, const float* __restrict__ fcb0,
                 const float* __restrict__ fcW, const float* __restrict__ fcb,
                 const int* __restrict__ y, float* __restrict__ out, int G)
{
    int tid = blockIdx.x * 256 + threadIdx.x;
    int total = G * 10;
    if (tid < total) {
        int g = tid / 10, c = tid % 10;
        float acc = fcb0[c];
        const float* pxg = px + (size_t)g * 32;
        #pragma unroll
        for (int k = 0; k < 32; k++) acc = fmaf(pxg[k], fcW0[k * 10 + c], acc);
        #pragma unroll
        for (int i = 0; i < 4; i++) {
            acc += fcb[i * 10 + c];
            const float* pg = pl + ((size_t)i * G + g) * 64;
            const float* w  = fcW + i * 640;
            #pragma unroll
            for (int k = 0; k < 64; k++) acc = fmaf(pg[k], w[k * 10 + c], acc);
        }
        out[tid] = acc;
    } else if (tid < total + G) {
        out[tid] = (float)y[tid - total];
    }
}

// ---------------------------------------------------------------------------
extern "C" void kernel_launch(void* const* d_in, const int* in_sizes, int n_in,
                              void* d_out, int out_size, void* d_ws, size_t ws_size,
                              hipStream_t stream)
{
    const float* x     = (const float*)d_in[0];
    const int*   ei    = (const int*)  d_in[1];
    const int*   batch = (const int*)  d_in[2];
    const int*   y     = (const int*)  d_in[3];
    const float* W_enc = (const float*)d_in[4];
    const float* b_enc = (const float*)d_in[5];
    const float* W1    = (const float*)d_in[6];
    const float* b1    = (const float*)d_in[7];
    const float* g1    = (const float*)d_in[8];
    const float* be1   = (const float*)d_in[9];
    const float* W2    = (const float*)d_in[10];
    const float* b2    = (const float*)d_in[11];
    const float* gout  = (const float*)d_in[12];
    const float* bout  = (const float*)d_in[13];
    const float* fcW0  = (const float*)d_in[14];
    const float* fcb0  = (const float*)d_in[15];
    const float* fcW   = (const float*)d_in[16];
    const float* fcb   = (const float*)d_in[17];

    const int N = in_sizes[0] / 32;   // 100000
    const int E = in_sizes[1] / 2;    // 1600000
    const int G = in_sizes[3];        // 2000
    const int* src = ei;
    const int* dst = ei + E;

    float* ws = (float*)d_ws;
    const size_t ND = (size_t)N * 64;
    float* h     = ws;
    float* agg   = h + ND;
    float* t     = agg + ND;
    float* stats = t + ND;               // [4][2] x (sum64, sumsq64) = 1024 f
    float* ss    = stats + 1024;         // [4][2] x 128 = 1024 f
    float* px    = ss + 1024;            // G*32
    float* pl    = px + (size_t)G * 32;  // 4*G*64

    // zero stats + ss + pooled regions (ws is poisoned 0xAA before every call)
    size_t zbytes = (size_t)(1024 + 1024 + G * 32 + 4 * G * 64) * sizeof(float);
    hipMemsetAsync(stats, 0, zbytes, stream);

    const int gemm_blocks = N / 32;  // N divisible by 32 (100000/32 = 3125)
    const float invN = 1.0f / (float)N;

    // encoder: h = x @ W_enc + b_enc
    mlp_gemm<32, 0, false><<<gemm_blocks, 256, 0, stream>>>(
        x, nullptr, nullptr, W_enc, b_enc, h, nullptr, nullptr);
    // JK pooling of raw x
    pool_x<<<(N * 32 + 255) / 256, 256, 0, stream>>>(x, batch, px, N);

    for (int i = 0; i < 4; i++) {
        float* s1a = stats + (i * 2 + 0) * 128;   // stage1 sum
        float* s1b = s1a + 64;                    // stage1 sumsq
        float* ss1 = ss + (i * 2 + 0) * 128;
        float* s2a = stats + (i * 2 + 1) * 128;   // stage2 sum
        float* s2b = s2a + 64;
        float* ss2 = ss + (i * 2 + 1) * 128;

        hipMemsetAsync(agg, 0, ND * sizeof(float), stream);
        scatter_add<<<(E * 16 + 255) / 256, 256, 0, stream>>>(src, dst, h, agg, E);

        // t = (h + agg) @ W1[i] + b1[i]   (+ column stats of t)
        mlp_gemm<64, 1, true><<<gemm_blocks, 256, 0, stream>>>(
            h, agg, nullptr, W1 + (size_t)i * 4096, b1 + i * 64, t, s1a, s1b);
        bn_finalize<<<1, 64, 0, stream>>>(s1a, s1b, g1 + i * 64, be1 + i * 64, ss1, invN);

        // t2(=agg) = relu(bn(t)) @ W2[i] + b2[i]   (+ column stats)
        mlp_gemm<64, 2, true><<<gemm_blocks, 256, 0, stream>>>(
            t, nullptr, ss1, W2 + (size_t)i * 4096, b2 + i * 64, agg, s2a, s2b);
        bn_finalize<<<1, 64, 0, stream>>>(s2a, s2b, gout + i * 64, bout + i * 64, ss2, invN);

        // h = relu(bn(t2)); pooled[i] += per-graph sum
        bn_relu_pool<<<(N * 64 + 255) / 256, 256, 0, stream>>>(
            agg, ss2, batch, h, pl + (size_t)i * G * 64, N);
    }

    head_kernel<<<(G * 10 + G + 255) / 256, 256, 0, stream>>>(
        px, pl, fcW0, fcb0, fcW, fcb, y, (float*)d_out, G);
}

// Round 2
// 1403.903 us; speedup vs baseline: 4.5748x; 4.5748x over previous
//
#include <hip/hip_runtime.h>

// GIN round 2: CSR-based atomic-free neighbor aggregation.
// CSR (counting sort of edges by dst) built once per call, reused for 4 layers.
// ws layout (floats): h | m (each N*64), stats[4][2][2][64], ss[4][2][128],
//                     px[G*32], pl[4][G*64], then ints: row[N+1], srcs[E].
// CSR-build int temps (deg, ex, bsum, cursor) alias the m buffer (unused until
// the first gather, which runs after CSR build completes).

#define BN_EPS 1e-5f

// ---------------------------------------------------------------------------
// GEMM: out[n][d] = transform(in)[n][:K] @ W[K][64] + bias[d]
// MODE 0: in = A
// MODE 2: in = relu(A*scale[k] + shift[k])   (BN+ReLU on the fly)
// STATS: per-column sum/sumsq of OUTPUT -> stat_sum/stat_sumsq (block-reduced + atomic)
// In-place safe (out==A): each block stages its own 32 rows in LDS pre-sync.
template<int K, int MODE, bool STATS>
__global__ __launch_bounds__(256)
void mlp_gemm(const float* __restrict__ A,
              const float* __restrict__ scale_shift,
              const float* __restrict__ W, const float* __restrict__ bias,
              float* __restrict__ out,
              float* __restrict__ stat_sum, float* __restrict__ stat_sumsq)
{
    __shared__ float W_lds[K * 64];
    __shared__ float in_lds[32 * K];
    const int tid = threadIdx.x;
    const int d   = tid & 63;
    const int nl  = tid >> 6;           // 0..3
    const int nb  = blockIdx.x * 32;

    #pragma unroll
    for (int i = tid; i < K * 64; i += 256) W_lds[i] = W[i];

    const float* Ab = A + (size_t)nb * K;
    #pragma unroll
    for (int i = tid; i < 32 * K; i += 256) {
        float v = Ab[i];
        if (MODE == 2) {
            int k = i % K;
            v = fmaxf(v * scale_shift[k] + scale_shift[64 + k], 0.f);
        }
        in_lds[i] = v;
    }
    __syncthreads();

    float acc[8];
    const float bv = bias[d];
    #pragma unroll
    for (int nn = 0; nn < 8; nn++) acc[nn] = bv;

    #pragma unroll
    for (int k = 0; k < K; k++) {
        float w = W_lds[k * 64 + d];
        #pragma unroll
        for (int nn = 0; nn < 8; nn++)
            acc[nn] = fmaf(in_lds[(nl + nn * 4) * K + k], w, acc[nn]);
    }

    float* ob = out + (size_t)nb * 64;
    #pragma unroll
    for (int nn = 0; nn < 8; nn++)
        ob[(nl + nn * 4) * 64 + d] = acc[nn];

    if (STATS) {
        float s1 = 0.f, s2 = 0.f;
        #pragma unroll
        for (int nn = 0; nn < 8; nn++) { s1 += acc[nn]; s2 += acc[nn] * acc[nn]; }
        __syncthreads();
        in_lds[tid]       = s1;
        in_lds[256 + tid] = s2;
        __syncthreads();
        if (nl == 0) {
            float t1 = in_lds[d] + in_lds[64 + d] + in_lds[128 + d] + in_lds[192 + d];
            float t2 = in_lds[256 + d] + in_lds[320 + d] + in_lds[384 + d] + in_lds[448 + d];
            unsafeAtomicAdd(&stat_sum[d],   t1);
            unsafeAtomicAdd(&stat_sumsq[d], t2);
        }
    }
}

// ---------------------------------------------------------------------------
// CSR build
__global__ __launch_bounds__(256)
void deg_count(const int* __restrict__ dst, int* __restrict__ deg, int E)
{
    int e = blockIdx.x * 256 + threadIdx.x;
    if (e < E) atomicAdd(&deg[dst[e]], 1);
}

// per-block exclusive scan of deg -> ex, block totals -> bsum
__global__ __launch_bounds__(256)
void scan_block(const int* __restrict__ deg, int* __restrict__ ex,
                int* __restrict__ bsum, int N)
{
    __shared__ int sm[256];
    int t = threadIdx.x;
    int i = blockIdx.x * 256 + t;
    int v = (i < N) ? deg[i] : 0;
    sm[t] = v; __syncthreads();
    for (int off = 1; off < 256; off <<= 1) {
        int add = (t >= off) ? sm[t - off] : 0;
        __syncthreads();
        sm[t] += add;
        __syncthreads();
    }
    if (i < N) ex[i] = sm[t] - v;           // exclusive
    if (t == 255) bsum[blockIdx.x] = sm[255];
}

// single-block exclusive scan of bsum (B <= 512)
__global__ __launch_bounds__(512)
void scan_top(int* __restrict__ bsum, int B)
{
    __shared__ int sm[512];
    int t = threadIdx.x;
    int v = (t < B) ? bsum[t] : 0;
    sm[t] = v; __syncthreads();
    for (int off = 1; off < 512; off <<= 1) {
        int add = (t >= off) ? sm[t - off] : 0;
        __syncthreads();
        sm[t] += add;
        __syncthreads();
    }
    if (t < B) bsum[t] = sm[t] - v;         // exclusive
}

__global__ __launch_bounds__(256)
void scan_finish(const int* __restrict__ ex, const int* __restrict__ bsum,
                 int* __restrict__ row, int* __restrict__ cursor, int N, int E)
{
    int i = blockIdx.x * 256 + threadIdx.x;
    if (i < N) {
        int r = ex[i] + bsum[blockIdx.x];
        row[i] = r;
        cursor[i] = r;
    }
    if (blockIdx.x == 0 && threadIdx.x == 0) row[N] = E;
}

__global__ __launch_bounds__(256)
void csr_fill(const int* __restrict__ src, const int* __restrict__ dst,
              int* __restrict__ cursor, int* __restrict__ srcs, int E)
{
    int e = blockIdx.x * 256 + threadIdx.x;
    if (e >= E) return;
    int p = atomicAdd(&cursor[dst[e]], 1);
    srcs[p] = src[e];
}

// ---------------------------------------------------------------------------
// m[n][:] = h[n][:] + sum_{s in nbrs(n)} h[s][:]   (GIN eps=0 self-term fused)
// 16 threads per node, float4 per thread.
__global__ __launch_bounds__(256)
void agg_gather(const int* __restrict__ row, const int* __restrict__ srcs,
                const float* __restrict__ h, float* __restrict__ m, int N)
{
    int tid = blockIdx.x * 256 + threadIdx.x;
    int n = tid >> 4;
    if (n >= N) return;
    int c4 = tid & 15;
    const float4* h4 = (const float4*)h;
    float4 acc = h4[(size_t)n * 16 + c4];
    int e = row[n], end = row[n + 1];
    // 2-way unroll for two independent gathers in flight
    for (; e + 1 < end; e += 2) {
        int s0 = srcs[e], s1 = srcs[e + 1];
        float4 v0 = h4[(size_t)s0 * 16 + c4];
        float4 v1 = h4[(size_t)s1 * 16 + c4];
        acc.x += v0.x + v1.x; acc.y += v0.y + v1.y;
        acc.z += v0.z + v1.z; acc.w += v0.w + v1.w;
    }
    if (e < end) {
        int s0 = srcs[e];
        float4 v0 = h4[(size_t)s0 * 16 + c4];
        acc.x += v0.x; acc.y += v0.y; acc.z += v0.z; acc.w += v0.w;
    }
    ((float4*)m)[(size_t)n * 16 + c4] = acc;
}

// ---------------------------------------------------------------------------
__global__ void bn_finalize(const float* __restrict__ sum, const float* __restrict__ sumsq,
                            const float* __restrict__ gamma, const float* __restrict__ beta,
                            float* __restrict__ ss, float invN)
{
    int d = threadIdx.x;  // 64
    float mu   = sum[d] * invN;
    float var  = sumsq[d] * invN - mu * mu;
    float rstd = rsqrtf(var + BN_EPS);
    float s    = gamma[d] * rstd;
    ss[d]      = s;
    ss[64 + d] = beta[d] - s * mu;
}

// h = relu(t2*scale+shift); pooled[batch[n]][d] += h
__global__ __launch_bounds__(256)
void bn_relu_pool(const float* __restrict__ t2, const float* __restrict__ ss,
                  const int* __restrict__ batch, float* __restrict__ h,
                  float* __restrict__ pooled, int N)
{
    int tid = blockIdx.x * 256 + threadIdx.x;
    int n = tid >> 6;
    if (n >= N) return;
    int d = tid & 63;
    float v = fmaxf(t2[tid] * ss[d] + ss[64 + d], 0.f);
    h[tid] = v;
    unsafeAtomicAdd(&pooled[(size_t)batch[n] * 64 + d], v);
}

__global__ __launch_bounds__(256)
void pool_x(const float* __restrict__ x, const int* __restrict__ batch,
            float* __restrict__ px, int N)
{
    int tid = blockIdx.x * 256 + threadIdx.x;
    int n = tid >> 5;
    if (n >= N) return;
    int f = tid & 31;
    unsafeAtomicAdd(&px[(size_t)batch[n] * 32 + f], x[tid]);
}

// ---------------------------------------------------------------------------
__global__ __launch_bounds__(256)
void head_kernel(const float* __restrict__ px, const float* __restrict__ pl,
                 const float* __restrict__ fcW0, const float* __restrict__ fcb0,
                 const float* __restrict__ fcW, const float* __restrict__ fcb,
                 const int* __restrict__ y, float* __restrict__ out, int G)
{
    int tid = blockIdx.x * 256 + threadIdx.x;
    int total = G * 10;
    if (tid < total) {
        int g = tid / 10, c = tid % 10;
        float acc = fcb0[c];
        const float* pxg = px + (size_t)g * 32;
        #pragma unroll
        for (int k = 0; k < 32; k++) acc = fmaf(pxg[k], fcW0[k * 10 + c], acc);
        #pragma unroll
        for (int i = 0; i < 4; i++) {
            acc += fcb[i * 10 + c];
            const float* pg = pl + ((size_t)i * G + g) * 64;
            const float* w  = fcW + i * 640;
            #pragma unroll
            for (int k = 0; k < 64; k++) acc = fmaf(pg[k], w[k * 10 + c], acc);
        }
        out[tid] = acc;
    } else if (tid < total + G) {
        out[tid] = (float)y[tid - total];
    }
}

// ---------------------------------------------------------------------------
extern "C" void kernel_launch(void* const* d_in, const int* in_sizes, int n_in,
                              void* d_out, int out_size, void* d_ws, size_t ws_size,
                              hipStream_t stream)
{
    const float* x     = (const float*)d_in[0];
    const int*   ei    = (const int*)  d_in[1];
    const int*   batch = (const int*)  d_in[2];
    const int*   y     = (const int*)  d_in[3];
    const float* W_enc = (const float*)d_in[4];
    const float* b_enc = (const float*)d_in[5];
    const float* W1    = (const float*)d_in[6];
    const float* b1    = (const float*)d_in[7];
    const float* g1    = (const float*)d_in[8];
    const float* be1   = (const float*)d_in[9];
    const float* W2    = (const float*)d_in[10];
    const float* b2    = (const float*)d_in[11];
    const float* gout  = (const float*)d_in[12];
    const float* bout  = (const float*)d_in[13];
    const float* fcW0  = (const float*)d_in[14];
    const float* fcb0  = (const float*)d_in[15];
    const float* fcW   = (const float*)d_in[16];
    const float* fcb   = (const float*)d_in[17];

    const int N = in_sizes[0] / 32;   // 100000
    const int E = in_sizes[1] / 2;    // 1600000
    const int G = in_sizes[3];        // 2000
    const int* src = ei;
    const int* dst = ei + E;

    float* ws = (float*)d_ws;
    const size_t ND = (size_t)N * 64;
    float* h     = ws;
    float* m     = h + ND;
    float* stats = m + ND;               // [4][2] x (sum64,sumsq64) = 1024 f
    float* ss    = stats + 1024;         // 1024 f
    float* px    = ss + 1024;            // G*32
    float* pl    = px + (size_t)G * 32;  // 4*G*64
    int*   row   = (int*)(pl + (size_t)4 * G * 64);  // N+1
    int*   srcs  = row + (N + 1);                     // E
    // CSR-build temps alias m (m unused until after csr_fill)
    int*   deg    = (int*)m;       // N
    int*   ex     = deg + N;       // N
    int*   bsum   = ex + N;        // 512
    int*   cursor = bsum + 512;    // N

    const int SB = (N + 255) / 256;   // scan blocks (391)

    // zero stats/ss/px/pl and deg
    size_t zbytes = (size_t)(1024 + 1024 + G * 32 + 4 * G * 64) * sizeof(float);
    hipMemsetAsync(stats, 0, zbytes, stream);
    hipMemsetAsync(deg, 0, (size_t)N * sizeof(int), stream);

    // ---- CSR build (once, reused by all 4 layers)
    deg_count<<<(E + 255) / 256, 256, 0, stream>>>(dst, deg, E);
    scan_block<<<SB, 256, 0, stream>>>(deg, ex, bsum, N);
    scan_top<<<1, 512, 0, stream>>>(bsum, SB);
    scan_finish<<<SB, 256, 0, stream>>>(ex, bsum, row, cursor, N, E);
    csr_fill<<<(E + 255) / 256, 256, 0, stream>>>(src, dst, cursor, srcs, E);

    const int gemm_blocks = N / 32;   // 3125
    const float invN = 1.0f / (float)N;

    // encoder: h = x @ W_enc + b_enc
    mlp_gemm<32, 0, false><<<gemm_blocks, 256, 0, stream>>>(
        x, nullptr, W_enc, b_enc, h, nullptr, nullptr);
    pool_x<<<(N * 32 + 255) / 256, 256, 0, stream>>>(x, batch, px, N);

    for (int i = 0; i < 4; i++) {
        float* s1a = stats + (i * 2 + 0) * 128;
        float* s1b = s1a + 64;
        float* ss1 = ss + (i * 2 + 0) * 128;
        float* s2a = stats + (i * 2 + 1) * 128;
        float* s2b = s2a + 64;
        float* ss2 = ss + (i * 2 + 1) * 128;

        // m = h + sum_nbrs h   (atomic-free gather)
        agg_gather<<<(N * 16 + 255) / 256, 256, 0, stream>>>(row, srcs, h, m, N);

        // m = m @ W1[i] + b1[i]  (in-place) + stats
        mlp_gemm<64, 0, true><<<gemm_blocks, 256, 0, stream>>>(
            m, nullptr, W1 + (size_t)i * 4096, b1 + i * 64, m, s1a, s1b);
        bn_finalize<<<1, 64, 0, stream>>>(s1a, s1b, g1 + i * 64, be1 + i * 64, ss1, invN);

        // m = relu(bn(m)) @ W2[i] + b2[i]  (in-place) + stats
        mlp_gemm<64, 2, true><<<gemm_blocks, 256, 0, stream>>>(
            m, ss1, W2 + (size_t)i * 4096, b2 + i * 64, m, s2a, s2b);
        bn_finalize<<<1, 64, 0, stream>>>(s2a, s2b, gout + i * 64, bout + i * 64, ss2, invN);

        // h = relu(bn(m)); pl[i][g] += h
        bn_relu_pool<<<(N * 64 + 255) / 256, 256, 0, stream>>>(
            m, ss2, batch, h, pl + (size_t)i * G * 64, N);
    }

    head_kernel<<<(G * 10 + G + 255) / 256, 256, 0, stream>>>(
        px, pl, fcW0, fcb0, fcW, fcb, y, (float*)d_out, G);
}

// Round 3
// 942.813 us; speedup vs baseline: 6.8121x; 1.4891x over previous
//
#include <hip/hip_runtime.h>

// GIN round 3: register-tiled fp32 GEMM (8x4 per thread, ds_read_b128),
// BN+ReLU fused into CSR gather, pool-only epilogue with run-length atomics.
// Buffers ping-pong between h and m; GEMMs run in-place (block reads only its
// own 128 rows into LDS before storing).

#define BN_EPS 1e-5f

// ---------------------------------------------------------------------------
// GEMM: out[n][d] = transform(in)[n][:K] @ W[K][64] + bias[d]
// MODE 0: in = A
// MODE 2: in = relu(A*scale[k] + shift[k])
// STATS: per-column sum/sumsq of OUTPUT -> stat_sum/stat_sumsq
// Block: 256 threads; tile 128 nodes x 64 cols; thread tile 8 nodes x 4 cols.
// LDS: in (stride K+4), W^T (stride K+1) -> all reads ds_read_b128, <=2-way banks.
template<int K, int MODE, bool STATS>
__global__ __launch_bounds__(256)
void mlp_gemm(const float* __restrict__ A,
              const float* __restrict__ scale_shift,
              const float* __restrict__ W, const float* __restrict__ bias,
              float* __restrict__ out,
              float* __restrict__ stat_sum, float* __restrict__ stat_sumsq,
              int N)
{
    constexpr int SIN = K + 4;   // in_lds row stride (floats)
    constexpr int SWT = K + 1;   // wt_lds row stride
    constexpr int F4R = K / 4;   // float4 per input row
    constexpr int FSH = (K == 64) ? 4 : 3;

    __shared__ float in_lds[128 * SIN];
    __shared__ float wt_lds[64 * SWT];

    const int tid = threadIdx.x;
    const int tx  = tid & 15;          // d-group: cols 4*tx .. 4*tx+3
    const int ty  = tid >> 4;          // node-group: rows ty + 16*r
    const int nb  = blockIdx.x * 128;

    // stage W^T: wt_lds[d][k] = W[k][d]
    for (int idx = tid; idx < K * 64; idx += 256) {
        int k = idx >> 6, d = idx & 63;
        wt_lds[d * SWT + k] = W[idx];
    }

    // stage input rows (with optional BN+ReLU transform), zero-fill invalid rows
    for (int f = tid; f < 128 * F4R; f += 256) {
        int rloc = f >> FSH;
        int k0   = (f & (F4R - 1)) * 4;
        int row  = nb + rloc;
        float4 v = make_float4(0.f, 0.f, 0.f, 0.f);
        if (row < N) {
            v = ((const float4*)A)[(size_t)row * F4R + (k0 >> 2)];
            if (MODE == 2) {
                float4 s4 = ((const float4*)scale_shift)[k0 >> 2];
                float4 h4 = ((const float4*)scale_shift)[16 + (k0 >> 2)];
                v.x = fmaxf(fmaf(v.x, s4.x, h4.x), 0.f);
                v.y = fmaxf(fmaf(v.y, s4.y, h4.y), 0.f);
                v.z = fmaxf(fmaf(v.z, s4.z, h4.z), 0.f);
                v.w = fmaxf(fmaf(v.w, s4.w, h4.w), 0.f);
            }
        }
        *(float4*)&in_lds[rloc * SIN + k0] = v;
    }
    __syncthreads();

    float acc[8][4];
    {
        float4 b4 = ((const float4*)bias)[tx];
        #pragma unroll
        for (int r = 0; r < 8; r++) {
            acc[r][0] = b4.x; acc[r][1] = b4.y; acc[r][2] = b4.z; acc[r][3] = b4.w;
        }
    }

    #pragma unroll 2
    for (int k0 = 0; k0 < K; k0 += 4) {
        float4 w0 = *(const float4*)&wt_lds[(4 * tx + 0) * SWT + k0];
        float4 w1 = *(const float4*)&wt_lds[(4 * tx + 1) * SWT + k0];
        float4 w2 = *(const float4*)&wt_lds[(4 * tx + 2) * SWT + k0];
        float4 w3 = *(const float4*)&wt_lds[(4 * tx + 3) * SWT + k0];
        #pragma unroll
        for (int r = 0; r < 8; r++) {
            float4 a4 = *(const float4*)&in_lds[(ty + 16 * r) * SIN + k0];
            acc[r][0] = fmaf(a4.x, w0.x, fmaf(a4.y, w0.y, fmaf(a4.z, w0.z, fmaf(a4.w, w0.w, acc[r][0]))));
            acc[r][1] = fmaf(a4.x, w1.x, fmaf(a4.y, w1.y, fmaf(a4.z, w1.z, fmaf(a4.w, w1.w, acc[r][1]))));
            acc[r][2] = fmaf(a4.x, w2.x, fmaf(a4.y, w2.y, fmaf(a4.z, w2.z, fmaf(a4.w, w2.w, acc[r][2]))));
            acc[r][3] = fmaf(a4.x, w3.x, fmaf(a4.y, w3.y, fmaf(a4.z, w3.z, fmaf(a4.w, w3.w, acc[r][3]))));
        }
    }

    #pragma unroll
    for (int r = 0; r < 8; r++) {
        int row = nb + ty + 16 * r;
        if (row < N)
            *(float4*)&out[(size_t)row * 64 + 4 * tx] =
                make_float4(acc[r][0], acc[r][1], acc[r][2], acc[r][3]);
    }

    if (STATS) {
        float s1[4] = {0.f, 0.f, 0.f, 0.f};
        float s2[4] = {0.f, 0.f, 0.f, 0.f};
        #pragma unroll
        for (int r = 0; r < 8; r++) {
            if (nb + ty + 16 * r < N) {
                #pragma unroll
                for (int i = 0; i < 4; i++) {
                    s1[i] += acc[r][i];
                    s2[i] += acc[r][i] * acc[r][i];
                }
            }
        }
        __syncthreads();              // done with in_lds; reuse for reduction
        float* red = in_lds;          // [16][64] sums + [16][64] sumsq
        #pragma unroll
        for (int i = 0; i < 4; i++) {
            red[ty * 64 + 4 * tx + i]        = s1[i];
            red[1024 + ty * 64 + 4 * tx + i] = s2[i];
        }
        __syncthreads();
        if (tid < 64) {
            float t1 = 0.f, t2 = 0.f;
            #pragma unroll
            for (int t = 0; t < 16; t++) {
                t1 += red[t * 64 + tid];
                t2 += red[1024 + t * 64 + tid];
            }
            unsafeAtomicAdd(&stat_sum[tid],   t1);
            unsafeAtomicAdd(&stat_sumsq[tid], t2);
        }
    }
}

// ---------------------------------------------------------------------------
// CSR build
__global__ __launch_bounds__(256)
void deg_count(const int* __restrict__ dst, int* __restrict__ deg, int E)
{
    int e = blockIdx.x * 256 + threadIdx.x;
    if (e < E) atomicAdd(&deg[dst[e]], 1);
}

__global__ __launch_bounds__(256)
void scan_block(const int* __restrict__ deg, int* __restrict__ ex,
                int* __restrict__ bsum, int N)
{
    __shared__ int sm[256];
    int t = threadIdx.x;
    int i = blockIdx.x * 256 + t;
    int v = (i < N) ? deg[i] : 0;
    sm[t] = v; __syncthreads();
    for (int off = 1; off < 256; off <<= 1) {
        int add = (t >= off) ? sm[t - off] : 0;
        __syncthreads();
        sm[t] += add;
        __syncthreads();
    }
    if (i < N) ex[i] = sm[t] - v;
    if (t == 255) bsum[blockIdx.x] = sm[255];
}

__global__ __launch_bounds__(512)
void scan_top(int* __restrict__ bsum, int B)
{
    __shared__ int sm[512];
    int t = threadIdx.x;
    int v = (t < B) ? bsum[t] : 0;
    sm[t] = v; __syncthreads();
    for (int off = 1; off < 512; off <<= 1) {
        int add = (t >= off) ? sm[t - off] : 0;
        __syncthreads();
        sm[t] += add;
        __syncthreads();
    }
    if (t < B) bsum[t] = sm[t] - v;
}

__global__ __launch_bounds__(256)
void scan_finish(const int* __restrict__ ex, const int* __restrict__ bsum,
                 int* __restrict__ row, int* __restrict__ cursor, int N, int E)
{
    int i = blockIdx.x * 256 + threadIdx.x;
    if (i < N) {
        int r = ex[i] + bsum[blockIdx.x];
        row[i] = r;
        cursor[i] = r;
    }
    if (blockIdx.x == 0 && threadIdx.x == 0) row[N] = E;
}

__global__ __launch_bounds__(256)
void csr_fill(const int* __restrict__ src, const int* __restrict__ dst,
              int* __restrict__ cursor, int* __restrict__ srcs, int E)
{
    int e = blockIdx.x * 256 + threadIdx.x;
    if (e >= E) return;
    int p = atomicAdd(&cursor[dst[e]], 1);
    srcs[p] = src[e];
}

// ---------------------------------------------------------------------------
// nxt[n] = t(cur[n]) + sum_{s in nbrs(n)} t(cur[s]),  t = BN? relu(v*s+sh) : v
template<bool BN>
__global__ __launch_bounds__(256)
void agg_gather(const int* __restrict__ row, const int* __restrict__ srcs,
                const float* __restrict__ cur, const float* __restrict__ ss,
                float* __restrict__ nxt, int N)
{
    int tid = blockIdx.x * 256 + threadIdx.x;
    int n = tid >> 4;
    if (n >= N) return;
    int c4 = tid & 15;
    float4 s4, h4;
    if (BN) {
        s4 = ((const float4*)ss)[c4];
        h4 = ((const float4*)ss)[16 + c4];
    }
    const float4* cur4 = (const float4*)cur;

    float4 v = cur4[(size_t)n * 16 + c4];
    if (BN) {
        v.x = fmaxf(fmaf(v.x, s4.x, h4.x), 0.f);
        v.y = fmaxf(fmaf(v.y, s4.y, h4.y), 0.f);
        v.z = fmaxf(fmaf(v.z, s4.z, h4.z), 0.f);
        v.w = fmaxf(fmaf(v.w, s4.w, h4.w), 0.f);
    }
    float4 acc = v;

    int e = row[n], end = row[n + 1];
    for (; e + 1 < end; e += 2) {
        int a = srcs[e], b = srcs[e + 1];
        float4 v0 = cur4[(size_t)a * 16 + c4];
        float4 v1 = cur4[(size_t)b * 16 + c4];
        if (BN) {
            v0.x = fmaxf(fmaf(v0.x, s4.x, h4.x), 0.f);
            v0.y = fmaxf(fmaf(v0.y, s4.y, h4.y), 0.f);
            v0.z = fmaxf(fmaf(v0.z, s4.z, h4.z), 0.f);
            v0.w = fmaxf(fmaf(v0.w, s4.w, h4.w), 0.f);
            v1.x = fmaxf(fmaf(v1.x, s4.x, h4.x), 0.f);
            v1.y = fmaxf(fmaf(v1.y, s4.y, h4.y), 0.f);
            v1.z = fmaxf(fmaf(v1.z, s4.z, h4.z), 0.f);
            v1.w = fmaxf(fmaf(v1.w, s4.w, h4.w), 0.f);
        }
        acc.x += v0.x + v1.x; acc.y += v0.y + v1.y;
        acc.z += v0.z + v1.z; acc.w += v0.w + v1.w;
    }
    if (e < end) {
        int a = srcs[e];
        float4 v0 = cur4[(size_t)a * 16 + c4];
        if (BN) {
            v0.x = fmaxf(fmaf(v0.x, s4.x, h4.x), 0.f);
            v0.y = fmaxf(fmaf(v0.y, s4.y, h4.y), 0.f);
            v0.z = fmaxf(fmaf(v0.z, s4.z, h4.z), 0.f);
            v0.w = fmaxf(fmaf(v0.w, s4.w, h4.w), 0.f);
        }
        acc.x += v0.x; acc.y += v0.y; acc.z += v0.z; acc.w += v0.w;
    }
    ((float4*)nxt)[(size_t)n * 16 + c4] = acc;
}

// ---------------------------------------------------------------------------
__global__ void bn_finalize(const float* __restrict__ sum, const float* __restrict__ sumsq,
                            const float* __restrict__ gamma, const float* __restrict__ beta,
                            float* __restrict__ ss, float invN)
{
    int d = threadIdx.x;  // 64
    float mu   = sum[d] * invN;
    float var  = sumsq[d] * invN - mu * mu;
    float rstd = rsqrtf(var + BN_EPS);
    float s    = gamma[d] * rstd;
    ss[d]      = s;
    ss[64 + d] = beta[d] - s * mu;
}

// pooled[batch[n]][d] += relu(m[n][d]*s+sh)  — run-length accumulate (batch sorted)
__global__ __launch_bounds__(256)
void pool_nodes(const float* __restrict__ m, const float* __restrict__ ss,
                const int* __restrict__ batch, float* __restrict__ pooled, int N)
{
    int d  = threadIdx.x & 63;
    int nl = threadIdx.x >> 6;     // 0..3
    int nb = blockIdx.x * 32;
    float s = ss[d], sh = ss[64 + d];
    float acc = 0.f;
    int cg = -1;
    #pragma unroll
    for (int r = 0; r < 8; r++) {
        int n = nb + nl * 8 + r;
        if (n >= N) break;
        int g = batch[n];
        if (g != cg) {
            if (cg >= 0) unsafeAtomicAdd(&pooled[(size_t)cg * 64 + d], acc);
            acc = 0.f; cg = g;
        }
        acc += fmaxf(fmaf(m[(size_t)n * 64 + d], s, sh), 0.f);
    }
    if (cg >= 0) unsafeAtomicAdd(&pooled[(size_t)cg * 64 + d], acc);
}

// px[batch[n]][f] += x[n][f]  — run-length accumulate
__global__ __launch_bounds__(256)
void pool_x(const float* __restrict__ x, const int* __restrict__ batch,
            float* __restrict__ px, int N)
{
    int f  = threadIdx.x & 31;
    int nl = threadIdx.x >> 5;     // 0..7
    int nb = blockIdx.x * 64;
    float acc = 0.f;
    int cg = -1;
    #pragma unroll
    for (int r = 0; r < 8; r++) {
        int n = nb + nl * 8 + r;
        if (n >= N) break;
        int g = batch[n];
        if (g != cg) {
            if (cg >= 0) unsafeAtomicAdd(&px[(size_t)cg * 32 + f], acc);
            acc = 0.f; cg = g;
        }
        acc += x[(size_t)n * 32 + f];
    }
    if (cg >= 0) unsafeAtomicAdd(&px[(size_t)cg * 32 + f], acc);
}

// ---------------------------------------------------------------------------
__global__ __launch_bounds__(256)
void head_kernel(const float* __restrict__ px, const float* __restrict__ pl,
                 const float* __restrict__ fcW0, const float* __restrict__ fcb0,
                 const float* __restrict__ fcW, const float* __restrict__ fcb,
                 const int* __restrict__ y, float* __restrict__ out, int G)
{
    int tid = blockIdx.x * 256 + threadIdx.x;
    int total = G * 10;
    if (tid < total) {
        int g = tid / 10, c = tid % 10;
        float acc = fcb0[c];
        const float* pxg = px + (size_t)g * 32;
        #pragma unroll
        for (int k = 0; k < 32; k++) acc = fmaf(pxg[k], fcW0[k * 10 + c], acc);
        #pragma unroll
        for (int i = 0; i < 4; i++) {
            acc += fcb[i * 10 + c];
            const float* pg = pl + ((size_t)i * G + g) * 64;
            const float* w  = fcW + i * 640;
            #pragma unroll
            for (int k = 0; k < 64; k++) acc = fmaf(pg[k], w[k * 10 + c], acc);
        }
        out[tid] = acc;
    } else if (tid < total + G) {
        out[tid] = (float)y[tid - total];
    }
}

// ---------------------------------------------------------------------------
extern "C" void kernel_launch(void* const* d_in, const int* in_sizes, int n_in,
                              void* d_out, int out_size, void* d_ws, size_t ws_size,
                              hipStream_t stream)
{
    const float* x     = (const float*)d_in[0];
    const int*   ei    = (const int*)  d_in[1];
    const int*   batch = (const int*)  d_in[2];
    const int*   y     = (const int*)  d_in[3];
    const float* W_enc = (const float*)d_in[4];
    const float* b_enc = (const float*)d_in[5];
    const float* W1    = (const float*)d_in[6];
    const float* b1    = (const float*)d_in[7];
    const float* g1    = (const float*)d_in[8];
    const float* be1   = (const float*)d_in[9];
    const float* W2    = (const float*)d_in[10];
    const float* b2    = (const float*)d_in[11];
    const float* gout  = (const float*)d_in[12];
    const float* bout  = (const float*)d_in[13];
    const float* fcW0  = (const float*)d_in[14];
    const float* fcb0  = (const float*)d_in[15];
    const float* fcW   = (const float*)d_in[16];
    const float* fcb   = (const float*)d_in[17];

    const int N = in_sizes[0] / 32;   // 100000
    const int E = in_sizes[1] / 2;    // 1600000
    const int G = in_sizes[3];        // 2000
    const int* src = ei;
    const int* dst = ei + E;

    float* ws = (float*)d_ws;
    const size_t ND = (size_t)N * 64;
    float* h     = ws;
    float* m     = h + ND;
    float* stats = m + ND;               // [4][2] x (sum64,sumsq64) = 1024 f
    float* ss    = stats + 1024;         // 1024 f
    float* px    = ss + 1024;            // G*32
    float* pl    = px + (size_t)G * 32;  // 4*G*64
    int*   row   = (int*)(pl + (size_t)4 * G * 64);  // N+1
    int*   srcs  = row + (N + 1);                     // E
    // CSR-build temps alias m (unused until first gather)
    int*   deg    = (int*)m;
    int*   ex     = deg + N;
    int*   bsum   = ex + N;
    int*   cursor = bsum + 512;

    const int SB = (N + 255) / 256;

    size_t zbytes = (size_t)(1024 + 1024 + G * 32 + 4 * G * 64) * sizeof(float);
    hipMemsetAsync(stats, 0, zbytes, stream);
    hipMemsetAsync(deg, 0, (size_t)N * sizeof(int), stream);

    // CSR build (once)
    deg_count<<<(E + 255) / 256, 256, 0, stream>>>(dst, deg, E);
    scan_block<<<SB, 256, 0, stream>>>(deg, ex, bsum, N);
    scan_top<<<1, 512, 0, stream>>>(bsum, SB);
    scan_finish<<<SB, 256, 0, stream>>>(ex, bsum, row, cursor, N, E);
    csr_fill<<<(E + 255) / 256, 256, 0, stream>>>(src, dst, cursor, srcs, E);

    const int gb = (N + 127) / 128;   // GEMM blocks
    const float invN = 1.0f / (float)N;

    // encoder: h = x @ W_enc + b_enc
    mlp_gemm<32, 0, false><<<gb, 256, 0, stream>>>(
        x, nullptr, W_enc, b_enc, h, nullptr, nullptr, N);
    pool_x<<<(N + 63) / 64, 256, 0, stream>>>(x, batch, px, N);

    for (int i = 0; i < 4; i++) {
        float* s1a = stats + (i * 2 + 0) * 128;
        float* s1b = s1a + 64;
        float* ss1 = ss + (i * 2 + 0) * 128;
        float* s2a = stats + (i * 2 + 1) * 128;
        float* s2b = s2a + 64;
        float* ss2 = ss + (i * 2 + 1) * 128;

        float* cur = (i % 2 == 0) ? h : m;
        float* nxt = (i % 2 == 0) ? m : h;

        // nxt = t(cur[n]) + sum t(cur[nbr]);  t = BN+ReLU of previous layer (i>0)
        if (i == 0) {
            agg_gather<false><<<(N * 16 + 255) / 256, 256, 0, stream>>>(
                row, srcs, cur, nullptr, nxt, N);
        } else {
            float* ssp = ss + ((i - 1) * 2 + 1) * 128;
            agg_gather<true><<<(N * 16 + 255) / 256, 256, 0, stream>>>(
                row, srcs, cur, ssp, nxt, N);
        }

        // nxt = nxt @ W1[i] + b1[i]  (in-place) + stats
        mlp_gemm<64, 0, true><<<gb, 256, 0, stream>>>(
            nxt, nullptr, W1 + (size_t)i * 4096, b1 + i * 64, nxt, s1a, s1b, N);
        bn_finalize<<<1, 64, 0, stream>>>(s1a, s1b, g1 + i * 64, be1 + i * 64, ss1, invN);

        // nxt = relu(bn(nxt)) @ W2[i] + b2[i]  (in-place) + stats
        mlp_gemm<64, 2, true><<<gb, 256, 0, stream>>>(
            nxt, ss1, W2 + (size_t)i * 4096, b2 + i * 64, nxt, s2a, s2b, N);
        bn_finalize<<<1, 64, 0, stream>>>(s2a, s2b, gout + i * 64, bout + i * 64, ss2, invN);

        // pl[i][g] += relu(bn(nxt))
        pool_nodes<<<(N + 31) / 32, 256, 0, stream>>>(
            nxt, ss2, batch, pl + (size_t)i * G * 64, N);
    }

    head_kernel<<<(G * 10 + G + 255) / 256, 256, 0, stream>>>(
        px, pl, fcW0, fcb0, fcW, fcb, y, (float*)d_out, G);
}